// Round 4
// baseline (376.162 us; speedup 1.0000x reference)
//
#include <hip/hip_runtime.h>
#include <hip/hip_bf16.h>

typedef unsigned short u16;
typedef float f32x4 __attribute__((ext_vector_type(4)));
typedef __bf16 bf16x8 __attribute__((ext_vector_type(8)));
typedef unsigned short su8v __attribute__((ext_vector_type(8)));
typedef unsigned short su4v __attribute__((ext_vector_type(4)));

#define BB 8
#define NHD 8
#define DD 128
#define NN 1024
#define DIM 1024
#define H3 3072
#define MM 8192
#define PTS 72   // P LDS row stride (u16): 144B rows, b64 writes land conflict-min
// scale * log2(e), folded into Q weights so softmax is exp2(raw dot)
#define QSC (0.08838834764831845f * 1.4426950408889634f)

__constant__ int   d_IDX[16] = {0,1,2,3, 1,0,3,2, 2,3,0,1, 3,2,1,0};
__constant__ float d_SGN[16] = {1.f,-1.f,-1.f,-1.f, 1.f,1.f,1.f,-1.f,
                                1.f,-1.f,1.f,1.f,  1.f,1.f,-1.f,1.f};

__device__ __forceinline__ f32x4 mfma16(su8v a, su8v b, f32x4 c) {
  return __builtin_amdgcn_mfma_f32_16x16x32_bf16(
      __builtin_bit_cast(bf16x8, a), __builtin_bit_cast(bf16x8, b), c, 0, 0, 0);
}
__device__ __forceinline__ u16 f2b(float f) {  // RNE
  unsigned int u = __builtin_bit_cast(unsigned int, f);
  u += 0x7fffu + ((u >> 16) & 1u);
  return (u16)(u >> 16);
}
typedef const __attribute__((address_space(1))) unsigned int* gas_t;
typedef __attribute__((address_space(3))) unsigned int* las_t;
__device__ __forceinline__ void gll16(const u16* g, u16* l) {
  __builtin_amdgcn_global_load_lds((gas_t)g, (las_t)l, 16, 0, 0);
}

// ---------------------------------------------------------------------------
// prep_weff: effective weights [out_row][in_col] bf16; Q-rows pre-scaled by QSC
// ---------------------------------------------------------------------------
__global__ __launch_bounds__(256) void prep_weff(
    const float* __restrict__ wqkv, const float* __restrict__ wproj,
    u16* __restrict__ weffQ, u16* __restrict__ weffP) {
  int tid = blockIdx.x * 256 + threadIdx.x;
  int stride = gridDim.x * 256;
  for (int i = tid; i < H3 * DIM; i += stride) {
    int row = i >> 10, col = i & 1023;
    int q = row / 768, o = row - q * 768;
    int p = col >> 8, c = col & 255;
    float v = d_SGN[q * 4 + p] * wqkv[(d_IDX[q * 4 + p] * 768 + o) * 256 + c];
    if (o < 256) v *= QSC;  // Q rows
    weffQ[i] = f2b(v);
  }
  for (int i = tid; i < DIM * DIM; i += stride) {
    int row = i >> 10, col = i & 1023;
    int q = row >> 8, o = row & 255;
    int p = col >> 8, c = col & 255;
    weffP[i] = f2b(d_SGN[q * 4 + p] * wproj[(d_IDX[q * 4 + p] * 256 + o) * 256 + c]);
  }
}

// ---------------------------------------------------------------------------
// prep_x: x (B,Cc,4,N) fp32 -> Ax bf16 [8192 (b,n)][1024 (p,c)]
// ---------------------------------------------------------------------------
__global__ __launch_bounds__(256) void prep_x(
    const float* __restrict__ x, u16* __restrict__ Ax) {
  int id = blockIdx.x * 256 + threadIdx.x;
  const float4* xv = (const float4*)x;
  float4 f = xv[id];
  int n4 = id & 255;
  int rem = id >> 8;
  int p = rem & 3, c = (rem >> 2) & 255, b = rem >> 10;
  int col = p * 256 + c;
  size_t rbase = (size_t)(b * 1024 + n4 * 4) * 1024 + col;
  Ax[rbase] = f2b(f.x);
  Ax[rbase + 1024] = f2b(f.y);
  Ax[rbase + 2048] = f2b(f.z);
  Ax[rbase + 3072] = f2b(f.w);
}

// ---------------------------------------------------------------------------
// GEMM core: 128x128 tile, BK=64 (32 MFMA per barrier pair), gll staging.
// LDS tiles [128 rows][64 k] dense stride 64 (2-way alias on frag reads = free).
// ---------------------------------------------------------------------------
__device__ __forceinline__ void gemm_core2(
    const u16* __restrict__ Ag, const u16* __restrict__ Bg,
    u16* As, u16* Bs, int tid, f32x4 acc[4][4]) {
  int w = tid >> 6, lane = tid & 63, l16 = lane & 15, quad = lane >> 4;
  int mt = (w & 1) * 64, nt = (w >> 1) * 64;
  for (int k0 = 0; k0 < 1024; k0 += 64) {
    __syncthreads();
#pragma unroll
    for (int t = 0; t < 4; ++t) {
      int ci = w * 4 + t;
      int row = ci * 8 + (lane >> 3);
      int col = (lane & 7) * 8;
      gll16(Ag + (size_t)row * 1024 + k0 + col, As + ci * 512);
      gll16(Bg + (size_t)row * 1024 + k0 + col, Bs + ci * 512);
    }
    __syncthreads();
#pragma unroll
    for (int kk = 0; kk < 2; ++kk) {
      su8v af[4], bf[4];
#pragma unroll
      for (int i = 0; i < 4; ++i)
        af[i] = *(const su8v*)(As + (mt + i * 16 + l16) * 64 + kk * 32 + quad * 8);
#pragma unroll
      for (int j = 0; j < 4; ++j)
        bf[j] = *(const su8v*)(Bs + (nt + j * 16 + l16) * 64 + kk * 32 + quad * 8);
#pragma unroll
      for (int i = 0; i < 4; ++i)
#pragma unroll
        for (int j = 0; j < 4; ++j)
          acc[i][j] = mfma16(af[i], bf[j], acc[i][j]);
    }
  }
}

// ---------------------------------------------------------------------------
// QKV GEMM: scatter to Q [bh][n][128], K dense [bh][n][128], V^T [bh][d][n]
// ---------------------------------------------------------------------------
__global__ __launch_bounds__(256) void gemm_qkv_mfma(
    const u16* __restrict__ Ax, const u16* __restrict__ weffQ,
    const float* __restrict__ bqkv,
    u16* __restrict__ Qb, u16* __restrict__ Kb, u16* __restrict__ VbT) {
  __shared__ u16 As[128 * 64];
  __shared__ u16 Bs[128 * 64];
  int m0 = blockIdx.x * 128, n0 = blockIdx.y * 128;
  int tid = threadIdx.x;
  f32x4 acc[4][4];
#pragma unroll
  for (int i = 0; i < 4; ++i)
#pragma unroll
    for (int j = 0; j < 4; ++j) acc[i][j] = (f32x4){0.f, 0.f, 0.f, 0.f};
  gemm_core2(Ax + (size_t)m0 * 1024, weffQ + (size_t)n0 * 1024, As, Bs, tid, acc);

  int w = tid >> 6, lane = tid & 63, l16 = lane & 15, quad = lane >> 4;
  int mt = (w & 1) * 64, nt = (w >> 1) * 64;
#pragma unroll
  for (int j = 0; j < 4; ++j) {
    int n = n0 + nt + j * 16 + l16;
    int q = n / 768, o = n - q * 768;
    int sel = o >> 8, oc = o & 255;
    int ch = q * 256 + oc;
    int head = ch >> 7, d = ch & 127;
    float bias = bqkv[n];
    if (sel == 0) bias *= QSC;
#pragma unroll
    for (int i = 0; i < 4; ++i) {
#pragma unroll
      for (int r = 0; r < 4; ++r) {
        int m = m0 + mt + i * 16 + quad * 4 + r;
        int b = m >> 10, npos = m & 1023;
        int bh = b * NHD + head;
        u16 val = f2b(acc[i][j][r] + bias);
        if (sel == 0)      Qb[((size_t)bh * NN + npos) * DD + d] = val;
        else if (sel == 1) Kb[((size_t)bh * NN + npos) * DD + d] = val;
        else               VbT[((size_t)bh * DD + d) * NN + npos] = val;
      }
    }
  }
}

// ---------------------------------------------------------------------------
// Flash attention: 512 blocks (bh x 8), 128 queries/block, 32 q/wave.
// S^T = K·Q^T (A=K, B=Q) so P's C-layout is key-contiguous per lane:
// P writes are 8x ds_write_b64 instead of 32x ds_write_u16; row-sum is a
// single per-lane scalar. K staged dense via XOR-swizzled global_load_lds.
// ---------------------------------------------------------------------------
__global__ __launch_bounds__(256) void attn_mfma(
    const u16* __restrict__ Qb, const u16* __restrict__ Kb,
    const u16* __restrict__ VbT, u16* __restrict__ AO) {
  __shared__ u16 Ks[64 * 128];     // 16384 B, xor-swizzled 16B blocks
  __shared__ u16 Vt[128 * 64];     // 16384 B, dense
  __shared__ u16 Ps[4 * 32 * PTS]; // 18432 B
  int qt = blockIdx.x & 7, bh = blockIdx.x >> 3;
  int n0 = qt * 128;
  int tid = threadIdx.x;
  int w = tid >> 6, lane = tid & 63, l16 = lane & 15, quad = lane >> 4;
  const u16* Qg = Qb + ((size_t)bh * NN + n0) * DD;
  const u16* Kg = Kb + (size_t)bh * NN * DD;
  const u16* Vg = VbT + (size_t)bh * DD * NN;
  u16* Pw = Ps + w * 32 * PTS;

  su8v qreg[2][4];  // B-fragment: n=q (l16), k=d
#pragma unroll
  for (int mi = 0; mi < 2; ++mi)
#pragma unroll
    for (int ch = 0; ch < 4; ++ch)
      qreg[mi][ch] = *(const su8v*)(Qg + (size_t)(w * 32 + mi * 16 + l16) * DD +
                                    ch * 32 + quad * 8);

  float ls[2] = {0.f, 0.f};  // per-lane partial row-sum for q = l16
  f32x4 accO[2][8];
#pragma unroll
  for (int mi = 0; mi < 2; ++mi)
#pragma unroll
    for (int dt = 0; dt < 8; ++dt) accO[mi][dt] = (f32x4){0.f, 0.f, 0.f, 0.f};

  for (int kt = 0; kt < 16; ++kt) {
    int c0 = kt * 64;
    __syncthreads();
#pragma unroll
    for (int t = 0; t < 4; ++t) {
      int ci = w * 4 + t;
      // K: rows of 256B = 16 x 16B blocks; block xor-swizzled by row&7
      int krow = ci * 4 + (lane >> 4);
      int kblk = (lane & 15) ^ (krow & 7);
      gll16(Kg + (size_t)(c0 + krow) * DD + kblk * 8, Ks + ci * 512);
      // V^T: dense [d][64 keys]
      int dv = ci * 8 + (lane >> 3), cv = (lane & 7) * 8;
      gll16(Vg + (size_t)dv * NN + c0 + cv, Vt + ci * 512);
    }
    __syncthreads();

    // S^T[key][q]: A = K-frag (m=key), B = Q-frag (n=q)
    f32x4 sacc[2][4];
#pragma unroll
    for (int mi = 0; mi < 2; ++mi)
#pragma unroll
      for (int j = 0; j < 4; ++j) sacc[mi][j] = (f32x4){0.f, 0.f, 0.f, 0.f};
#pragma unroll
    for (int j = 0; j < 4; ++j) {
#pragma unroll
      for (int ch = 0; ch < 4; ++ch) {
        su8v kf = *(const su8v*)(Ks + (j * 16 + l16) * 128 +
                                 (((ch * 4 + quad) ^ (l16 & 7)) * 8));
        sacc[0][j] = mfma16(kf, qreg[0][ch], sacc[0][j]);
        sacc[1][j] = mfma16(kf, qreg[1][ch], sacc[1][j]);
      }
    }

    // p = 2^s; pack 4 key-contiguous values -> one b64 LDS write
#pragma unroll
    for (int mi = 0; mi < 2; ++mi)
#pragma unroll
      for (int j = 0; j < 4; ++j) {
        su4v pk;
#pragma unroll
        for (int r = 0; r < 4; ++r) {
          float p = __builtin_exp2f(sacc[mi][j][r]);
          ls[mi] += p;
          pk[r] = (u16)(__builtin_bit_cast(unsigned int, p) >> 16);
        }
        *(su4v*)(Pw + (mi * 16 + l16) * PTS + j * 16 + quad * 4) = pk;
      }

    // O += P V  (wave-local LDS round trip; DS pipe in-order per wave)
#pragma unroll
    for (int ch = 0; ch < 2; ++ch) {
      su8v pf0 = *(const su8v*)(Pw + l16 * PTS + ch * 32 + quad * 8);
      su8v pf1 = *(const su8v*)(Pw + (16 + l16) * PTS + ch * 32 + quad * 8);
#pragma unroll
      for (int dt = 0; dt < 8; ++dt) {
        su8v vf = *(const su8v*)(Vt + (dt * 16 + l16) * 64 + ch * 32 + quad * 8);
        accO[0][dt] = mfma16(pf0, vf, accO[0][dt]);
        accO[1][dt] = mfma16(pf1, vf, accO[1][dt]);
      }
    }
  }

  // row-sum: reduce over quad lanes (bits 4,5), then broadcast to acc rows
#pragma unroll
  for (int mi = 0; mi < 2; ++mi) {
    float s = ls[mi];
    s += __shfl_xor(s, 16, 64);
    s += __shfl_xor(s, 32, 64);
    ls[mi] = s;
  }
  int b = bh >> 3, head = bh & 7;
#pragma unroll
  for (int mi = 0; mi < 2; ++mi)
#pragma unroll
    for (int r = 0; r < 4; ++r) {
      float inv = 1.0f / __shfl(ls[mi], quad * 4 + r, 64);
      size_t rowbase =
          (size_t)(b * 1024 + n0 + w * 32 + mi * 16 + quad * 4 + r) * 1024 +
          head * 128;
#pragma unroll
      for (int dt = 0; dt < 8; ++dt)
        AO[rowbase + dt * 16 + l16] = f2b(accO[mi][dt][r] * inv);
    }
}

// ---------------------------------------------------------------------------
// quaternion depthwise 3x3 conv (fp32) — writes base term of out
// ---------------------------------------------------------------------------
__global__ __launch_bounds__(256) void qdwconv_kernel(
    const float* __restrict__ x, const float* __restrict__ wpe,
    const float* __restrict__ bpe, float* __restrict__ out) {
  int blk = blockIdx.x;
  int co = blk & 255;
  int b = blk >> 8;
  __shared__ float pl[4][34 * 34];
  __shared__ float wsm[4][9];
  int tid = threadIdx.x;
  for (int i = tid; i < 4 * 34 * 34; i += 256) ((float*)pl)[i] = 0.f;
  if (tid < 36) wsm[tid / 9][tid % 9] = wpe[((tid / 9) * 256 + co) * 9 + tid % 9];
  __syncthreads();
  for (int i = tid; i < 4 * 1024; i += 256) {
    int p = i >> 10, n = i & 1023;
    int h = n >> 5, ww = n & 31;
    pl[p][(h + 1) * 34 + (ww + 1)] =
        x[(((size_t)b * 256 + co) * 4 + p) * 1024 + n];
  }
  __syncthreads();
  for (int n = tid; n < 1024; n += 256) {
    int h = n >> 5, ww = n & 31;
    float in[4][9];
#pragma unroll
    for (int p = 0; p < 4; ++p)
#pragma unroll
      for (int t = 0; t < 9; ++t)
        in[p][t] = pl[p][(h + t / 3) * 34 + (ww + t % 3)];
#pragma unroll
    for (int q = 0; q < 4; ++q) {
      float acc = bpe[q * 256 + co];
#pragma unroll
      for (int p = 0; p < 4; ++p) {
        int idx = d_IDX[q * 4 + p];
        float s = d_SGN[q * 4 + p];
        float sub = 0.f;
#pragma unroll
        for (int t = 0; t < 9; ++t) sub += in[p][t] * wsm[idx][t];
        acc += s * sub;
      }
      out[(((size_t)b * 256 + co) * 4 + q) * 1024 + n] = acc;
    }
  }
}

// ---------------------------------------------------------------------------
// proj GEMM (swapped orientation): C[m=(q,o)][n=bn]; epilogue += into out
// ---------------------------------------------------------------------------
__global__ __launch_bounds__(256) void gemm_proj_mfma(
    const u16* __restrict__ AO, const u16* __restrict__ weffP,
    const float* __restrict__ bproj, float* __restrict__ out) {
  __shared__ u16 As[128 * 64];
  __shared__ u16 Bs[128 * 64];
  int n0 = blockIdx.x * 128;  // bn
  int m0 = blockIdx.y * 128;  // (q,o)
  int tid = threadIdx.x;
  f32x4 acc[4][4];
#pragma unroll
  for (int i = 0; i < 4; ++i)
#pragma unroll
    for (int j = 0; j < 4; ++j) acc[i][j] = (f32x4){0.f, 0.f, 0.f, 0.f};
  gemm_core2(weffP + (size_t)m0 * 1024, AO + (size_t)n0 * 1024, As, Bs, tid, acc);

  int w = tid >> 6, lane = tid & 63, l16 = lane & 15, quad = lane >> 4;
  int mt = (w & 1) * 64, nt = (w >> 1) * 64;
#pragma unroll
  for (int i = 0; i < 4; ++i) {
#pragma unroll
    for (int r = 0; r < 4; ++r) {
      int mrow = m0 + mt + i * 16 + quad * 4 + r;
      int q = mrow >> 8, o = mrow & 255;
      float bias = bproj[mrow];
#pragma unroll
      for (int j = 0; j < 4; ++j) {
        int n = n0 + nt + j * 16 + l16;
        int b = n >> 10, npos = n & 1023;
        size_t oidx = (((size_t)b * 256 + o) * 4 + q) * 1024 + npos;
        out[oidx] += acc[i][j][r] + bias;
      }
    }
  }
}

// ---------------------------------------------------------------------------
extern "C" void kernel_launch(void* const* d_in, const int* in_sizes, int n_in,
                              void* d_out, int out_size, void* d_ws,
                              size_t ws_size, hipStream_t stream) {
  const float* x      = (const float*)d_in[0];
  const float* w_qkv  = (const float*)d_in[1];
  const float* b_qkv  = (const float*)d_in[2];
  const float* w_proj = (const float*)d_in[3];
  const float* b_proj = (const float*)d_in[4];
  const float* w_pe   = (const float*)d_in[5];
  const float* b_pe   = (const float*)d_in[6];
  float* out = (float*)d_out;

  u16* ws = (u16*)d_ws;
  u16* weffQ = ws;                                   // 3072*1024
  u16* weffP = weffQ + (size_t)H3 * DIM;             // 1024*1024
  u16* Ax    = weffP + (size_t)DIM * DIM;            // 8192*1024
  u16* Qb    = Ax + (size_t)MM * DIM;                // 64*1024*128
  u16* Kb    = Qb + (size_t)BB * NHD * NN * DD;      // 64*1024*128
  u16* VbT   = Kb + (size_t)BB * NHD * NN * DD;      // 64*128*1024
  u16* AO    = VbT + (size_t)BB * NHD * DD * NN;     // 8192*1024
  // total ~92 MB bf16 scratch

  hipLaunchKernelGGL(prep_weff, dim3(4096), dim3(256), 0, stream,
                     w_qkv, w_proj, weffQ, weffP);
  hipLaunchKernelGGL(prep_x, dim3(8192), dim3(256), 0, stream, x, Ax);
  hipLaunchKernelGGL(gemm_qkv_mfma, dim3(MM / 128, H3 / 128), dim3(256), 0,
                     stream, Ax, weffQ, b_qkv, Qb, Kb, VbT);
  hipLaunchKernelGGL(attn_mfma, dim3(BB * NHD * 8), dim3(256), 0, stream,
                     Qb, Kb, VbT, AO);
  hipLaunchKernelGGL(qdwconv_kernel, dim3(BB * 256), dim3(256), 0, stream,
                     x, w_pe, b_pe, out);
  hipLaunchKernelGGL(gemm_proj_mfma, dim3(MM / 128, DIM / 128), dim3(256), 0,
                     stream, AO, weffP, b_proj, out);
}

// Round 6
// 357.085 us; speedup vs baseline: 1.0534x; 1.0534x over previous
//
#include <hip/hip_runtime.h>
#include <hip/hip_bf16.h>

typedef unsigned short u16;
typedef float f32x4 __attribute__((ext_vector_type(4)));
typedef __bf16 bf16x8 __attribute__((ext_vector_type(8)));
typedef unsigned short su8v __attribute__((ext_vector_type(8)));
typedef unsigned short su4v __attribute__((ext_vector_type(4)));

#define BB 8
#define NHD 8
#define DD 128
#define NN 1024
#define DIM 1024
#define H3 3072
#define MM 8192
#define PTS 72   // P LDS row stride (u16)
// scale * log2(e), folded into Q weights so softmax is exp2(raw dot)
#define QSC (0.08838834764831845f * 1.4426950408889634f)

__constant__ int   d_IDX[16] = {0,1,2,3, 1,0,3,2, 2,3,0,1, 3,2,1,0};
__constant__ float d_SGN[16] = {1.f,-1.f,-1.f,-1.f, 1.f,1.f,1.f,-1.f,
                                1.f,-1.f,1.f,1.f,  1.f,1.f,-1.f,1.f};

__device__ __forceinline__ f32x4 mfma16(su8v a, su8v b, f32x4 c) {
  return __builtin_amdgcn_mfma_f32_16x16x32_bf16(
      __builtin_bit_cast(bf16x8, a), __builtin_bit_cast(bf16x8, b), c, 0, 0, 0);
}
__device__ __forceinline__ u16 f2b(float f) {  // RNE
  unsigned int u = __builtin_bit_cast(unsigned int, f);
  u += 0x7fffu + ((u >> 16) & 1u);
  return (u16)(u >> 16);
}
typedef const __attribute__((address_space(1))) unsigned int* gas_t;
typedef __attribute__((address_space(3))) unsigned int* las_t;
__device__ __forceinline__ void gll16(const u16* g, u16* l) {
  __builtin_amdgcn_global_load_lds((gas_t)g, (las_t)l, 16, 0, 0);
}

// ---------------------------------------------------------------------------
// prep_weff: effective weights [out_row][in_col] bf16; Q-rows pre-scaled by QSC
// ---------------------------------------------------------------------------
__global__ __launch_bounds__(256) void prep_weff(
    const float* __restrict__ wqkv, const float* __restrict__ wproj,
    u16* __restrict__ weffQ, u16* __restrict__ weffP) {
  int tid = blockIdx.x * 256 + threadIdx.x;
  int stride = gridDim.x * 256;
  for (int i = tid; i < H3 * DIM; i += stride) {
    int row = i >> 10, col = i & 1023;
    int q = row / 768, o = row - q * 768;
    int p = col >> 8, c = col & 255;
    float v = d_SGN[q * 4 + p] * wqkv[(d_IDX[q * 4 + p] * 768 + o) * 256 + c];
    if (o < 256) v *= QSC;  // Q rows
    weffQ[i] = f2b(v);
  }
  for (int i = tid; i < DIM * DIM; i += stride) {
    int row = i >> 10, col = i & 1023;
    int q = row >> 8, o = row & 255;
    int p = col >> 8, c = col & 255;
    weffP[i] = f2b(d_SGN[q * 4 + p] * wproj[(d_IDX[q * 4 + p] * 256 + o) * 256 + c]);
  }
}

// ---------------------------------------------------------------------------
// prep_x: x (B,Cc,4,N) fp32 -> Ax bf16 [8192 (b,n)][1024 (p,c)]
// ---------------------------------------------------------------------------
__global__ __launch_bounds__(256) void prep_x(
    const float* __restrict__ x, u16* __restrict__ Ax) {
  int id = blockIdx.x * 256 + threadIdx.x;
  const float4* xv = (const float4*)x;
  float4 f = xv[id];
  int n4 = id & 255;
  int rem = id >> 8;
  int p = rem & 3, c = (rem >> 2) & 255, b = rem >> 10;
  int col = p * 256 + c;
  size_t rbase = (size_t)(b * 1024 + n4 * 4) * 1024 + col;
  Ax[rbase] = f2b(f.x);
  Ax[rbase + 1024] = f2b(f.y);
  Ax[rbase + 2048] = f2b(f.z);
  Ax[rbase + 3072] = f2b(f.w);
}

// ---------------------------------------------------------------------------
// GEMM core: 128x128 tile, BK=64 (32 MFMA per barrier pair), gll staging.
// LDS rows 64 u16 = 8 x 16B blocks, XOR-swizzled (blk ^= row&7) so fragment
// ds_read_b128 across l16 covers all 32 banks (2-way alias = free).
// ---------------------------------------------------------------------------
__device__ __forceinline__ void gemm_core2(
    const u16* __restrict__ Ag, const u16* __restrict__ Bg,
    u16* As, u16* Bs, int tid, f32x4 acc[4][4]) {
  int w = tid >> 6, lane = tid & 63, l16 = lane & 15, quad = lane >> 4;
  int mt = (w & 1) * 64, nt = (w >> 1) * 64;
  int srow = lane >> 3;                       // row&7 within staging
  int scol = ((lane & 7) ^ srow) * 8;         // swizzled global block
  int x7 = l16 & 7;                           // row&7 for fragment reads
  for (int k0 = 0; k0 < 1024; k0 += 64) {
    __syncthreads();
#pragma unroll
    for (int t = 0; t < 4; ++t) {
      int ci = w * 4 + t;
      int row = ci * 8 + srow;
      gll16(Ag + (size_t)row * 1024 + k0 + scol, As + ci * 512);
      gll16(Bg + (size_t)row * 1024 + k0 + scol, Bs + ci * 512);
    }
    __syncthreads();
#pragma unroll
    for (int kk = 0; kk < 2; ++kk) {
      su8v af[4], bf[4];
#pragma unroll
      for (int i = 0; i < 4; ++i)
        af[i] = *(const su8v*)(As + (mt + i * 16 + l16) * 64 +
                               ((kk * 4 + quad) ^ x7) * 8);
#pragma unroll
      for (int j = 0; j < 4; ++j)
        bf[j] = *(const su8v*)(Bs + (nt + j * 16 + l16) * 64 +
                               ((kk * 4 + quad) ^ x7) * 8);
#pragma unroll
      for (int i = 0; i < 4; ++i)
#pragma unroll
        for (int j = 0; j < 4; ++j)
          acc[i][j] = mfma16(af[i], bf[j], acc[i][j]);
    }
  }
}

// ---------------------------------------------------------------------------
// QKV GEMM: scatter to Q [bh][n][128], K dense [bh][n][128], V^T [bh][d][n]
// ---------------------------------------------------------------------------
__global__ __launch_bounds__(256) void gemm_qkv_mfma(
    const u16* __restrict__ Ax, const u16* __restrict__ weffQ,
    const float* __restrict__ bqkv,
    u16* __restrict__ Qb, u16* __restrict__ Kb, u16* __restrict__ VbT) {
  __shared__ u16 As[128 * 64];
  __shared__ u16 Bs[128 * 64];
  int m0 = blockIdx.x * 128, n0 = blockIdx.y * 128;
  int tid = threadIdx.x;
  f32x4 acc[4][4];
#pragma unroll
  for (int i = 0; i < 4; ++i)
#pragma unroll
    for (int j = 0; j < 4; ++j) acc[i][j] = (f32x4){0.f, 0.f, 0.f, 0.f};
  gemm_core2(Ax + (size_t)m0 * 1024, weffQ + (size_t)n0 * 1024, As, Bs, tid, acc);

  int w = tid >> 6, lane = tid & 63, l16 = lane & 15, quad = lane >> 4;
  int mt = (w & 1) * 64, nt = (w >> 1) * 64;
#pragma unroll
  for (int j = 0; j < 4; ++j) {
    int n = n0 + nt + j * 16 + l16;
    int q = n / 768, o = n - q * 768;
    int sel = o >> 8, oc = o & 255;
    int ch = q * 256 + oc;
    int head = ch >> 7, d = ch & 127;
    float bias = bqkv[n];
    if (sel == 0) bias *= QSC;
#pragma unroll
    for (int i = 0; i < 4; ++i) {
#pragma unroll
      for (int r = 0; r < 4; ++r) {
        int m = m0 + mt + i * 16 + quad * 4 + r;
        int b = m >> 10, npos = m & 1023;
        int bh = b * NHD + head;
        u16 val = f2b(acc[i][j][r] + bias);
        if (sel == 0)      Qb[((size_t)bh * NN + npos) * DD + d] = val;
        else if (sel == 1) Kb[((size_t)bh * NN + npos) * DD + d] = val;
        else               VbT[((size_t)bh * DD + d) * NN + npos] = val;
      }
    }
  }
}

// ---------------------------------------------------------------------------
// Flash attention: 512 blocks (bh x 8), 128 queries/block, 32 q/wave.
// S^T = K·Q^T; K and V^T tiles XOR-swizzled in LDS (conflict-free reads).
// ---------------------------------------------------------------------------
__global__ __launch_bounds__(256) void attn_mfma(
    const u16* __restrict__ Qb, const u16* __restrict__ Kb,
    const u16* __restrict__ VbT, u16* __restrict__ AO) {
  __shared__ u16 Ks[64 * 128];     // 16384 B, xor-swizzled 16B blocks
  __shared__ u16 Vt[128 * 64];     // 16384 B, xor-swizzled 16B blocks
  __shared__ u16 Ps[4 * 32 * PTS]; // 18432 B
  int qt = blockIdx.x & 7, bh = blockIdx.x >> 3;
  int n0 = qt * 128;
  int tid = threadIdx.x;
  int w = tid >> 6, lane = tid & 63, l16 = lane & 15, quad = lane >> 4;
  const u16* Qg = Qb + ((size_t)bh * NN + n0) * DD;
  const u16* Kg = Kb + (size_t)bh * NN * DD;
  const u16* Vg = VbT + (size_t)bh * DD * NN;
  u16* Pw = Ps + w * 32 * PTS;
  int x7 = l16 & 7;

  su8v qreg[2][4];  // B-fragment: n=q (l16), k=d
#pragma unroll
  for (int mi = 0; mi < 2; ++mi)
#pragma unroll
    for (int ch = 0; ch < 4; ++ch)
      qreg[mi][ch] = *(const su8v*)(Qg + (size_t)(w * 32 + mi * 16 + l16) * DD +
                                    ch * 32 + quad * 8);

  float ls[2] = {0.f, 0.f};  // per-lane partial row-sum for q = l16
  f32x4 accO[2][8];
#pragma unroll
  for (int mi = 0; mi < 2; ++mi)
#pragma unroll
    for (int dt = 0; dt < 8; ++dt) accO[mi][dt] = (f32x4){0.f, 0.f, 0.f, 0.f};

  for (int kt = 0; kt < 16; ++kt) {
    int c0 = kt * 64;
    __syncthreads();
#pragma unroll
    for (int t = 0; t < 4; ++t) {
      int ci = w * 4 + t;
      // K: rows of 256B = 16 x 16B blocks; block low-3-bits xor row&7
      int krow = ci * 4 + (lane >> 4);
      int kblk = (lane & 15) ^ (krow & 7);
      gll16(Kg + (size_t)(c0 + krow) * DD + kblk * 8, Ks + ci * 512);
      // V^T: rows of 128B = 8 x 16B blocks; xor-swizzled
      int dv = ci * 8 + (lane >> 3);
      int vblk = (lane & 7) ^ (dv & 7);
      gll16(Vg + (size_t)dv * NN + c0 + vblk * 8, Vt + ci * 512);
    }
    __syncthreads();

    // S^T[key][q]: A = K-frag (m=key), B = Q-frag (n=q)
    f32x4 sacc[2][4];
#pragma unroll
    for (int mi = 0; mi < 2; ++mi)
#pragma unroll
      for (int j = 0; j < 4; ++j) sacc[mi][j] = (f32x4){0.f, 0.f, 0.f, 0.f};
#pragma unroll
    for (int j = 0; j < 4; ++j) {
#pragma unroll
      for (int ch = 0; ch < 4; ++ch) {
        su8v kf = *(const su8v*)(Ks + (j * 16 + l16) * 128 +
                                 (((ch * 4 + quad) ^ x7) * 8));
        sacc[0][j] = mfma16(kf, qreg[0][ch], sacc[0][j]);
        sacc[1][j] = mfma16(kf, qreg[1][ch], sacc[1][j]);
      }
    }

    // p = 2^s; pack 4 key-contiguous values -> one b64 LDS write
#pragma unroll
    for (int mi = 0; mi < 2; ++mi)
#pragma unroll
      for (int j = 0; j < 4; ++j) {
        su4v pk;
#pragma unroll
        for (int r = 0; r < 4; ++r) {
          float p = __builtin_exp2f(sacc[mi][j][r]);
          ls[mi] += p;
          pk[r] = (u16)(__builtin_bit_cast(unsigned int, p) >> 16);
        }
        *(su4v*)(Pw + (mi * 16 + l16) * PTS + j * 16 + quad * 4) = pk;
      }

    // O += P V  (wave-local LDS round trip; DS pipe in-order per wave)
#pragma unroll
    for (int ch = 0; ch < 2; ++ch) {
      su8v pf0 = *(const su8v*)(Pw + l16 * PTS + ch * 32 + quad * 8);
      su8v pf1 = *(const su8v*)(Pw + (16 + l16) * PTS + ch * 32 + quad * 8);
#pragma unroll
      for (int dt = 0; dt < 8; ++dt) {
        su8v vf = *(const su8v*)(Vt + (dt * 16 + l16) * 64 +
                                 (((ch * 4 + quad) ^ x7) * 8));
        accO[0][dt] = mfma16(pf0, vf, accO[0][dt]);
        accO[1][dt] = mfma16(pf1, vf, accO[1][dt]);
      }
    }
  }

  // row-sum: reduce over quad lanes (bits 4,5), then broadcast to acc rows
#pragma unroll
  for (int mi = 0; mi < 2; ++mi) {
    float s = ls[mi];
    s += __shfl_xor(s, 16, 64);
    s += __shfl_xor(s, 32, 64);
    ls[mi] = s;
  }
  int b = bh >> 3, head = bh & 7;
#pragma unroll
  for (int mi = 0; mi < 2; ++mi)
#pragma unroll
    for (int r = 0; r < 4; ++r) {
      float inv = 1.0f / __shfl(ls[mi], quad * 4 + r, 64);
      size_t rowbase =
          (size_t)(b * 1024 + n0 + w * 32 + mi * 16 + quad * 4 + r) * 1024 +
          head * 128;
#pragma unroll
      for (int dt = 0; dt < 8; ++dt)
        AO[rowbase + dt * 16 + l16] = f2b(accO[mi][dt][r] * inv);
    }
}

// ---------------------------------------------------------------------------
// quaternion depthwise 3x3 conv (fp32) — writes PE term into workspace
// ---------------------------------------------------------------------------
__global__ __launch_bounds__(256) void qdwconv_kernel(
    const float* __restrict__ x, const float* __restrict__ wpe,
    const float* __restrict__ bpe, float* __restrict__ pe) {
  int blk = blockIdx.x;
  int co = blk & 255;
  int b = blk >> 8;
  __shared__ float pl[4][34 * 34];
  __shared__ float wsm[4][9];
  int tid = threadIdx.x;
  for (int i = tid; i < 4 * 34 * 34; i += 256) ((float*)pl)[i] = 0.f;
  if (tid < 36) wsm[tid / 9][tid % 9] = wpe[((tid / 9) * 256 + co) * 9 + tid % 9];
  __syncthreads();
  for (int i = tid; i < 4 * 1024; i += 256) {
    int p = i >> 10, n = i & 1023;
    int h = n >> 5, ww = n & 31;
    pl[p][(h + 1) * 34 + (ww + 1)] =
        x[(((size_t)b * 256 + co) * 4 + p) * 1024 + n];
  }
  __syncthreads();
  for (int n = tid; n < 1024; n += 256) {
    int h = n >> 5, ww = n & 31;
    float in[4][9];
#pragma unroll
    for (int p = 0; p < 4; ++p)
#pragma unroll
      for (int t = 0; t < 9; ++t)
        in[p][t] = pl[p][(h + t / 3) * 34 + (ww + t % 3)];
#pragma unroll
    for (int q = 0; q < 4; ++q) {
      float acc = bpe[q * 256 + co];
#pragma unroll
      for (int p = 0; p < 4; ++p) {
        int idx = d_IDX[q * 4 + p];
        float s = d_SGN[q * 4 + p];
        float sub = 0.f;
#pragma unroll
        for (int t = 0; t < 9; ++t) sub += in[p][t] * wsm[idx][t];
        acc += s * sub;
      }
      pe[(((size_t)b * 256 + co) * 4 + q) * 1024 + n] = acc;
    }
  }
}

// ---------------------------------------------------------------------------
// proj GEMM (swapped orientation): C[m=(q,o)][n=bn].
// Epilogue: out = PE + acc + bias (pure store — out has exactly one writer).
// ---------------------------------------------------------------------------
__global__ __launch_bounds__(256) void gemm_proj_mfma(
    const u16* __restrict__ AO, const u16* __restrict__ weffP,
    const float* __restrict__ bproj, const float* __restrict__ pe,
    float* __restrict__ out) {
  __shared__ u16 As[128 * 64];
  __shared__ u16 Bs[128 * 64];
  int n0 = blockIdx.x * 128;  // bn
  int m0 = blockIdx.y * 128;  // (q,o)
  int tid = threadIdx.x;
  f32x4 acc[4][4];
#pragma unroll
  for (int i = 0; i < 4; ++i)
#pragma unroll
    for (int j = 0; j < 4; ++j) acc[i][j] = (f32x4){0.f, 0.f, 0.f, 0.f};
  gemm_core2(weffP + (size_t)m0 * 1024, AO + (size_t)n0 * 1024, As, Bs, tid, acc);

  int w = tid >> 6, lane = tid & 63, l16 = lane & 15, quad = lane >> 4;
  int mt = (w & 1) * 64, nt = (w >> 1) * 64;
#pragma unroll
  for (int i = 0; i < 4; ++i) {
#pragma unroll
    for (int r = 0; r < 4; ++r) {
      int mrow = m0 + mt + i * 16 + quad * 4 + r;
      int q = mrow >> 8, o = mrow & 255;
      float bias = bproj[mrow];
#pragma unroll
      for (int j = 0; j < 4; ++j) {
        int n = n0 + nt + j * 16 + l16;
        int b = n >> 10, npos = n & 1023;
        size_t oidx = (((size_t)b * 256 + o) * 4 + q) * 1024 + npos;
        out[oidx] = pe[oidx] + acc[i][j][r] + bias;
      }
    }
  }
}

// ---------------------------------------------------------------------------
extern "C" void kernel_launch(void* const* d_in, const int* in_sizes, int n_in,
                              void* d_out, int out_size, void* d_ws,
                              size_t ws_size, hipStream_t stream) {
  const float* x      = (const float*)d_in[0];
  const float* w_qkv  = (const float*)d_in[1];
  const float* b_qkv  = (const float*)d_in[2];
  const float* w_proj = (const float*)d_in[3];
  const float* b_proj = (const float*)d_in[4];
  const float* w_pe   = (const float*)d_in[5];
  const float* b_pe   = (const float*)d_in[6];
  float* out = (float*)d_out;

  u16* ws = (u16*)d_ws;
  u16* weffQ = ws;                                   // 3072*1024
  u16* weffP = weffQ + (size_t)H3 * DIM;             // 1024*1024
  u16* Ax    = weffP + (size_t)DIM * DIM;            // 8192*1024
  u16* Qb    = Ax + (size_t)MM * DIM;                // 64*1024*128
  u16* Kb    = Qb + (size_t)BB * NHD * NN * DD;      // 64*1024*128
  u16* VbT   = Kb + (size_t)BB * NHD * NN * DD;      // 64*128*1024
  u16* AO    = VbT + (size_t)BB * NHD * DD * NN;     // 8192*1024
  float* PE  = (float*)(AO + (size_t)MM * DIM);      // 8192*1024 fp32
  // total ~125.8 MB scratch (R1 used 151 MB — fits)

  hipLaunchKernelGGL(prep_weff, dim3(4096), dim3(256), 0, stream,
                     w_qkv, w_proj, weffQ, weffP);
  hipLaunchKernelGGL(prep_x, dim3(8192), dim3(256), 0, stream, x, Ax);
  hipLaunchKernelGGL(gemm_qkv_mfma, dim3(MM / 128, H3 / 128), dim3(256), 0,
                     stream, Ax, weffQ, b_qkv, Qb, Kb, VbT);
  hipLaunchKernelGGL(attn_mfma, dim3(BB * NHD * 8), dim3(256), 0, stream,
                     Qb, Kb, VbT, AO);
  hipLaunchKernelGGL(qdwconv_kernel, dim3(BB * 256), dim3(256), 0, stream,
                     x, w_pe, b_pe, PE);
  hipLaunchKernelGGL(gemm_proj_mfma, dim3(MM / 128, DIM / 128), dim3(256), 0,
                     stream, AO, weffP, b_proj, PE, out);
}

// Round 7
// 335.578 us; speedup vs baseline: 1.1209x; 1.0641x over previous
//
#include <hip/hip_runtime.h>
#include <hip/hip_bf16.h>

typedef unsigned short u16;
typedef float f32x4 __attribute__((ext_vector_type(4)));
typedef __bf16 bf16x8 __attribute__((ext_vector_type(8)));
typedef unsigned short su8v __attribute__((ext_vector_type(8)));
typedef unsigned short su4v __attribute__((ext_vector_type(4)));

#define BB 8
#define NHD 8
#define DD 128
#define NN 1024
#define DIM 1024
#define H3 3072
#define MM 8192
#define PTS 72   // P LDS row stride (u16)
// scale * log2(e), folded into Q weights so softmax is exp2(raw dot)
#define QSC (0.08838834764831845f * 1.4426950408889634f)

__constant__ int   d_IDX[16] = {0,1,2,3, 1,0,3,2, 2,3,0,1, 3,2,1,0};
__constant__ float d_SGN[16] = {1.f,-1.f,-1.f,-1.f, 1.f,1.f,1.f,-1.f,
                                1.f,-1.f,1.f,1.f,  1.f,1.f,-1.f,1.f};

__device__ __forceinline__ f32x4 mfma16(su8v a, su8v b, f32x4 c) {
  return __builtin_amdgcn_mfma_f32_16x16x32_bf16(
      __builtin_bit_cast(bf16x8, a), __builtin_bit_cast(bf16x8, b), c, 0, 0, 0);
}
__device__ __forceinline__ u16 f2b(float f) {  // RNE
  unsigned int u = __builtin_bit_cast(unsigned int, f);
  u += 0x7fffu + ((u >> 16) & 1u);
  return (u16)(u >> 16);
}
typedef const __attribute__((address_space(1))) unsigned int* gas_t;
typedef __attribute__((address_space(3))) unsigned int* las_t;
__device__ __forceinline__ void gll16(const u16* g, u16* l) {
  __builtin_amdgcn_global_load_lds((gas_t)g, (las_t)l, 16, 0, 0);
}

// ---------------------------------------------------------------------------
// prep_weff: effective weights [out_row][in_col] bf16; Q-rows pre-scaled by QSC
// ---------------------------------------------------------------------------
__global__ __launch_bounds__(256) void prep_weff(
    const float* __restrict__ wqkv, const float* __restrict__ wproj,
    u16* __restrict__ weffQ, u16* __restrict__ weffP) {
  int tid = blockIdx.x * 256 + threadIdx.x;
  int stride = gridDim.x * 256;
  for (int i = tid; i < H3 * DIM; i += stride) {
    int row = i >> 10, col = i & 1023;
    int q = row / 768, o = row - q * 768;
    int p = col >> 8, c = col & 255;
    float v = d_SGN[q * 4 + p] * wqkv[(d_IDX[q * 4 + p] * 768 + o) * 256 + c];
    if (o < 256) v *= QSC;  // Q rows
    weffQ[i] = f2b(v);
  }
  for (int i = tid; i < DIM * DIM; i += stride) {
    int row = i >> 10, col = i & 1023;
    int q = row >> 8, o = row & 255;
    int p = col >> 8, c = col & 255;
    weffP[i] = f2b(d_SGN[q * 4 + p] * wproj[(d_IDX[q * 4 + p] * 256 + o) * 256 + c]);
  }
}

// ---------------------------------------------------------------------------
// prep_x: x (B,Cc,4,N) fp32 -> Ax bf16 [8192 (b,n)][1024 (p,c)]
// ---------------------------------------------------------------------------
__global__ __launch_bounds__(256) void prep_x(
    const float* __restrict__ x, u16* __restrict__ Ax) {
  int id = blockIdx.x * 256 + threadIdx.x;
  const float4* xv = (const float4*)x;
  float4 f = xv[id];
  int n4 = id & 255;
  int rem = id >> 8;
  int p = rem & 3, c = (rem >> 2) & 255, b = rem >> 10;
  int col = p * 256 + c;
  size_t rbase = (size_t)(b * 1024 + n4 * 4) * 1024 + col;
  Ax[rbase] = f2b(f.x);
  Ax[rbase + 1024] = f2b(f.y);
  Ax[rbase + 2048] = f2b(f.z);
  Ax[rbase + 3072] = f2b(f.w);
}

// ---------------------------------------------------------------------------
// GEMM core: 128x128 tile, BK=64 (32 MFMA per barrier pair), gll staging.
// LDS rows 64 u16 = 8 x 16B blocks, XOR-swizzled (blk ^= row&7) so fragment
// ds_read_b128 across l16 covers all 32 banks (2-way alias = free).
// A/B-symmetric: callers choose orientation by argument order.
// ---------------------------------------------------------------------------
__device__ __forceinline__ void gemm_core2(
    const u16* __restrict__ Ag, const u16* __restrict__ Bg,
    u16* As, u16* Bs, int tid, f32x4 acc[4][4]) {
  int w = tid >> 6, lane = tid & 63, l16 = lane & 15, quad = lane >> 4;
  int mt = (w & 1) * 64, nt = (w >> 1) * 64;
  int srow = lane >> 3;                       // row&7 within staging
  int scol = ((lane & 7) ^ srow) * 8;         // swizzled global block
  int x7 = l16 & 7;                           // row&7 for fragment reads
  for (int k0 = 0; k0 < 1024; k0 += 64) {
    __syncthreads();
#pragma unroll
    for (int t = 0; t < 4; ++t) {
      int ci = w * 4 + t;
      int row = ci * 8 + srow;
      gll16(Ag + (size_t)row * 1024 + k0 + scol, As + ci * 512);
      gll16(Bg + (size_t)row * 1024 + k0 + scol, Bs + ci * 512);
    }
    __syncthreads();
#pragma unroll
    for (int kk = 0; kk < 2; ++kk) {
      su8v af[4], bf[4];
#pragma unroll
      for (int i = 0; i < 4; ++i)
        af[i] = *(const su8v*)(As + (mt + i * 16 + l16) * 64 +
                               ((kk * 4 + quad) ^ x7) * 8);
#pragma unroll
      for (int j = 0; j < 4; ++j)
        bf[j] = *(const su8v*)(Bs + (nt + j * 16 + l16) * 64 +
                               ((kk * 4 + quad) ^ x7) * 8);
#pragma unroll
      for (int i = 0; i < 4; ++i)
#pragma unroll
        for (int j = 0; j < 4; ++j)
          acc[i][j] = mfma16(af[i], bf[j], acc[i][j]);
    }
  }
}

// ---------------------------------------------------------------------------
// QKV GEMM. Each column-block (blockIdx.y, 128 chans) lies in exactly one of
// Q/K/V and one head. Orientation chosen per block so the C-layout's 4
// row-consecutive values per lane map onto the *contiguous* axis of the
// destination: Q/K (m=chan -> r=d-consecutive, store [bh][npos][d]);
// V (m=bn -> r=npos-consecutive, store V^T [bh][d][npos]). All stores b64.
// ---------------------------------------------------------------------------
__global__ __launch_bounds__(256) void gemm_qkv_mfma(
    const u16* __restrict__ Ax, const u16* __restrict__ weffQ,
    const float* __restrict__ bqkv,
    u16* __restrict__ Qb, u16* __restrict__ Kb, u16* __restrict__ VbT) {
  __shared__ u16 As[128 * 64];
  __shared__ u16 Bs[128 * 64];
  int m0 = blockIdx.x * 128;    // bn block
  int col0 = blockIdx.y * 128;  // chan block (row of weffQ)
  int qq = col0 / 768;          // quaternion component (uniform)
  int off = col0 - qq * 768;
  int sel = off >> 8;           // 0=Q 1=K 2=V (uniform)
  int head = (qq * 256 + (off & 255)) >> 7;  // uniform, block = one head
  int tid = threadIdx.x;
  int w = tid >> 6, lane = tid & 63, l16 = lane & 15, quad = lane >> 4;
  int mt = (w & 1) * 64, nt = (w >> 1) * 64;
  f32x4 acc[4][4];
#pragma unroll
  for (int i = 0; i < 4; ++i)
#pragma unroll
    for (int j = 0; j < 4; ++j) acc[i][j] = (f32x4){0.f, 0.f, 0.f, 0.f};

  if (sel == 2) {
    // ---- V: m=bn, n=chan ----
    gemm_core2(Ax + (size_t)m0 * 1024, weffQ + (size_t)col0 * 1024, As, Bs,
               tid, acc);
#pragma unroll
    for (int j = 0; j < 4; ++j) {
      int d = nt + j * 16 + l16;
      float bias = bqkv[col0 + nt + j * 16 + l16];
#pragma unroll
      for (int i = 0; i < 4; ++i) {
        int m = m0 + mt + i * 16 + quad * 4;
        int b = m >> 10, npos = m & 1023;
        int bh = b * NHD + head;
        su4v pk;
#pragma unroll
        for (int r = 0; r < 4; ++r) pk[r] = f2b(acc[i][j][r] + bias);
        *(su4v*)(VbT + ((size_t)bh * DD + d) * NN + npos) = pk;
      }
    }
  } else {
    // ---- Q/K: m=chan, n=bn ----
    gemm_core2(weffQ + (size_t)col0 * 1024, Ax + (size_t)m0 * 1024, As, Bs,
               tid, acc);
    u16* dst = (sel == 0) ? Qb : Kb;
    float sc = (sel == 0) ? (float)QSC : 1.0f;
#pragma unroll
    for (int i = 0; i < 4; ++i) {
      int dbase = mt + i * 16 + quad * 4;  // d of r=0 (mult of 4)
      float4 b4 = *(const float4*)(bqkv + col0 + dbase);
#pragma unroll
      for (int j = 0; j < 4; ++j) {
        int nglob = m0 + nt + j * 16 + l16;
        int b = nglob >> 10, npos = nglob & 1023;
        int bh = b * NHD + head;
        su4v pk;
        pk[0] = f2b(acc[i][j][0] + b4.x * sc);
        pk[1] = f2b(acc[i][j][1] + b4.y * sc);
        pk[2] = f2b(acc[i][j][2] + b4.z * sc);
        pk[3] = f2b(acc[i][j][3] + b4.w * sc);
        *(su4v*)(dst + ((size_t)bh * NN + npos) * DD + dbase) = pk;
      }
    }
  }
}

// ---------------------------------------------------------------------------
// Flash attention: 512 blocks (bh x 8), 128 queries/block, 32 q/wave.
// S^T = K·Q^T; K and V^T tiles XOR-swizzled in LDS (conflict-free reads).
// ---------------------------------------------------------------------------
__global__ __launch_bounds__(256) void attn_mfma(
    const u16* __restrict__ Qb, const u16* __restrict__ Kb,
    const u16* __restrict__ VbT, u16* __restrict__ AO) {
  __shared__ u16 Ks[64 * 128];     // 16384 B, xor-swizzled 16B blocks
  __shared__ u16 Vt[128 * 64];     // 16384 B, xor-swizzled 16B blocks
  __shared__ u16 Ps[4 * 32 * PTS]; // 18432 B
  int qt = blockIdx.x & 7, bh = blockIdx.x >> 3;
  int n0 = qt * 128;
  int tid = threadIdx.x;
  int w = tid >> 6, lane = tid & 63, l16 = lane & 15, quad = lane >> 4;
  const u16* Qg = Qb + ((size_t)bh * NN + n0) * DD;
  const u16* Kg = Kb + (size_t)bh * NN * DD;
  const u16* Vg = VbT + (size_t)bh * DD * NN;
  u16* Pw = Ps + w * 32 * PTS;
  int x7 = l16 & 7;

  su8v qreg[2][4];  // B-fragment: n=q (l16), k=d
#pragma unroll
  for (int mi = 0; mi < 2; ++mi)
#pragma unroll
    for (int ch = 0; ch < 4; ++ch)
      qreg[mi][ch] = *(const su8v*)(Qg + (size_t)(w * 32 + mi * 16 + l16) * DD +
                                    ch * 32 + quad * 8);

  float ls[2] = {0.f, 0.f};  // per-lane partial row-sum for q = l16
  f32x4 accO[2][8];
#pragma unroll
  for (int mi = 0; mi < 2; ++mi)
#pragma unroll
    for (int dt = 0; dt < 8; ++dt) accO[mi][dt] = (f32x4){0.f, 0.f, 0.f, 0.f};

  for (int kt = 0; kt < 16; ++kt) {
    int c0 = kt * 64;
    __syncthreads();
#pragma unroll
    for (int t = 0; t < 4; ++t) {
      int ci = w * 4 + t;
      // K: rows of 256B = 16 x 16B blocks; block low-3-bits xor row&7
      int krow = ci * 4 + (lane >> 4);
      int kblk = (lane & 15) ^ (krow & 7);
      gll16(Kg + (size_t)(c0 + krow) * DD + kblk * 8, Ks + ci * 512);
      // V^T: rows of 128B = 8 x 16B blocks; xor-swizzled
      int dv = ci * 8 + (lane >> 3);
      int vblk = (lane & 7) ^ (dv & 7);
      gll16(Vg + (size_t)dv * NN + c0 + vblk * 8, Vt + ci * 512);
    }
    __syncthreads();

    // S^T[key][q]: A = K-frag (m=key), B = Q-frag (n=q)
    f32x4 sacc[2][4];
#pragma unroll
    for (int mi = 0; mi < 2; ++mi)
#pragma unroll
      for (int j = 0; j < 4; ++j) sacc[mi][j] = (f32x4){0.f, 0.f, 0.f, 0.f};
#pragma unroll
    for (int j = 0; j < 4; ++j) {
#pragma unroll
      for (int ch = 0; ch < 4; ++ch) {
        su8v kf = *(const su8v*)(Ks + (j * 16 + l16) * 128 +
                                 (((ch * 4 + quad) ^ x7) * 8));
        sacc[0][j] = mfma16(kf, qreg[0][ch], sacc[0][j]);
        sacc[1][j] = mfma16(kf, qreg[1][ch], sacc[1][j]);
      }
    }

    // p = 2^s; pack 4 key-contiguous values -> one b64 LDS write
#pragma unroll
    for (int mi = 0; mi < 2; ++mi)
#pragma unroll
      for (int j = 0; j < 4; ++j) {
        su4v pk;
#pragma unroll
        for (int r = 0; r < 4; ++r) {
          float p = __builtin_exp2f(sacc[mi][j][r]);
          ls[mi] += p;
          pk[r] = (u16)(__builtin_bit_cast(unsigned int, p) >> 16);
        }
        *(su4v*)(Pw + (mi * 16 + l16) * PTS + j * 16 + quad * 4) = pk;
      }

    // O += P V  (wave-local LDS round trip; DS pipe in-order per wave)
#pragma unroll
    for (int ch = 0; ch < 2; ++ch) {
      su8v pf0 = *(const su8v*)(Pw + l16 * PTS + ch * 32 + quad * 8);
      su8v pf1 = *(const su8v*)(Pw + (16 + l16) * PTS + ch * 32 + quad * 8);
#pragma unroll
      for (int dt = 0; dt < 8; ++dt) {
        su8v vf = *(const su8v*)(Vt + (dt * 16 + l16) * 64 +
                                 (((ch * 4 + quad) ^ x7) * 8));
        accO[0][dt] = mfma16(pf0, vf, accO[0][dt]);
        accO[1][dt] = mfma16(pf1, vf, accO[1][dt]);
      }
    }
  }

  // row-sum: reduce over quad lanes (bits 4,5), then broadcast to acc rows
#pragma unroll
  for (int mi = 0; mi < 2; ++mi) {
    float s = ls[mi];
    s += __shfl_xor(s, 16, 64);
    s += __shfl_xor(s, 32, 64);
    ls[mi] = s;
  }
  int b = bh >> 3, head = bh & 7;
#pragma unroll
  for (int mi = 0; mi < 2; ++mi)
#pragma unroll
    for (int r = 0; r < 4; ++r) {
      float inv = 1.0f / __shfl(ls[mi], quad * 4 + r, 64);
      size_t rowbase =
          (size_t)(b * 1024 + n0 + w * 32 + mi * 16 + quad * 4 + r) * 1024 +
          head * 128;
#pragma unroll
      for (int dt = 0; dt < 8; ++dt)
        AO[rowbase + dt * 16 + l16] = f2b(accO[mi][dt][r] * inv);
    }
}

// ---------------------------------------------------------------------------
// quaternion depthwise 3x3 conv (fp32) — writes PE term into workspace
// ---------------------------------------------------------------------------
__global__ __launch_bounds__(256) void qdwconv_kernel(
    const float* __restrict__ x, const float* __restrict__ wpe,
    const float* __restrict__ bpe, float* __restrict__ pe) {
  int blk = blockIdx.x;
  int co = blk & 255;
  int b = blk >> 8;
  __shared__ float pl[4][34 * 34];
  __shared__ float wsm[4][9];
  int tid = threadIdx.x;
  for (int i = tid; i < 4 * 34 * 34; i += 256) ((float*)pl)[i] = 0.f;
  if (tid < 36) wsm[tid / 9][tid % 9] = wpe[((tid / 9) * 256 + co) * 9 + tid % 9];
  __syncthreads();
  for (int i = tid; i < 4 * 1024; i += 256) {
    int p = i >> 10, n = i & 1023;
    int h = n >> 5, ww = n & 31;
    pl[p][(h + 1) * 34 + (ww + 1)] =
        x[(((size_t)b * 256 + co) * 4 + p) * 1024 + n];
  }
  __syncthreads();
  for (int n = tid; n < 1024; n += 256) {
    int h = n >> 5, ww = n & 31;
    float in[4][9];
#pragma unroll
    for (int p = 0; p < 4; ++p)
#pragma unroll
      for (int t = 0; t < 9; ++t)
        in[p][t] = pl[p][(h + t / 3) * 34 + (ww + t % 3)];
#pragma unroll
    for (int q = 0; q < 4; ++q) {
      float acc = bpe[q * 256 + co];
#pragma unroll
      for (int p = 0; p < 4; ++p) {
        int idx = d_IDX[q * 4 + p];
        float s = d_SGN[q * 4 + p];
        float sub = 0.f;
#pragma unroll
        for (int t = 0; t < 9; ++t) sub += in[p][t] * wsm[idx][t];
        acc += s * sub;
      }
      pe[(((size_t)b * 256 + co) * 4 + q) * 1024 + n] = acc;
    }
  }
}

// ---------------------------------------------------------------------------
// proj GEMM (swapped orientation): C[m=(q,o)][n=bn].
// Epilogue: out = PE + acc + bias (pure store — out has exactly one writer).
// ---------------------------------------------------------------------------
__global__ __launch_bounds__(256) void gemm_proj_mfma(
    const u16* __restrict__ AO, const u16* __restrict__ weffP,
    const float* __restrict__ bproj, const float* __restrict__ pe,
    float* __restrict__ out) {
  __shared__ u16 As[128 * 64];
  __shared__ u16 Bs[128 * 64];
  int n0 = blockIdx.x * 128;  // bn
  int m0 = blockIdx.y * 128;  // (q,o)
  int tid = threadIdx.x;
  f32x4 acc[4][4];
#pragma unroll
  for (int i = 0; i < 4; ++i)
#pragma unroll
    for (int j = 0; j < 4; ++j) acc[i][j] = (f32x4){0.f, 0.f, 0.f, 0.f};
  gemm_core2(weffP + (size_t)m0 * 1024, AO + (size_t)n0 * 1024, As, Bs, tid, acc);

  int w = tid >> 6, lane = tid & 63, l16 = lane & 15, quad = lane >> 4;
  int mt = (w & 1) * 64, nt = (w >> 1) * 64;
#pragma unroll
  for (int i = 0; i < 4; ++i) {
#pragma unroll
    for (int r = 0; r < 4; ++r) {
      int mrow = m0 + mt + i * 16 + quad * 4 + r;
      int q = mrow >> 8, o = mrow & 255;
      float bias = bproj[mrow];
#pragma unroll
      for (int j = 0; j < 4; ++j) {
        int n = n0 + nt + j * 16 + l16;
        int b = n >> 10, npos = n & 1023;
        size_t oidx = (((size_t)b * 256 + o) * 4 + q) * 1024 + npos;
        out[oidx] = pe[oidx] + acc[i][j][r] + bias;
      }
    }
  }
}

// ---------------------------------------------------------------------------
extern "C" void kernel_launch(void* const* d_in, const int* in_sizes, int n_in,
                              void* d_out, int out_size, void* d_ws,
                              size_t ws_size, hipStream_t stream) {
  const float* x      = (const float*)d_in[0];
  const float* w_qkv  = (const float*)d_in[1];
  const float* b_qkv  = (const float*)d_in[2];
  const float* w_proj = (const float*)d_in[3];
  const float* b_proj = (const float*)d_in[4];
  const float* w_pe   = (const float*)d_in[5];
  const float* b_pe   = (const float*)d_in[6];
  float* out = (float*)d_out;

  u16* ws = (u16*)d_ws;
  u16* weffQ = ws;                                   // 3072*1024
  u16* weffP = weffQ + (size_t)H3 * DIM;             // 1024*1024
  u16* Ax    = weffP + (size_t)DIM * DIM;            // 8192*1024
  u16* Qb    = Ax + (size_t)MM * DIM;                // 64*1024*128
  u16* Kb    = Qb + (size_t)BB * NHD * NN * DD;      // 64*1024*128
  u16* VbT   = Kb + (size_t)BB * NHD * NN * DD;      // 64*128*1024
  u16* AO    = VbT + (size_t)BB * NHD * DD * NN;     // 8192*1024
  float* PE  = (float*)(AO + (size_t)MM * DIM);      // 8192*1024 fp32
  // total ~125.8 MB scratch

  hipLaunchKernelGGL(prep_weff, dim3(4096), dim3(256), 0, stream,
                     w_qkv, w_proj, weffQ, weffP);
  hipLaunchKernelGGL(prep_x, dim3(8192), dim3(256), 0, stream, x, Ax);
  hipLaunchKernelGGL(gemm_qkv_mfma, dim3(MM / 128, H3 / 128), dim3(256), 0,
                     stream, Ax, weffQ, b_qkv, Qb, Kb, VbT);
  hipLaunchKernelGGL(attn_mfma, dim3(BB * NHD * 8), dim3(256), 0, stream,
                     Qb, Kb, VbT, AO);
  hipLaunchKernelGGL(qdwconv_kernel, dim3(BB * 256), dim3(256), 0, stream,
                     x, w_pe, b_pe, PE);
  hipLaunchKernelGGL(gemm_proj_mfma, dim3(MM / 128, DIM / 128), dim3(256), 0,
                     stream, AO, weffP, b_proj, PE, out);
}

// Round 8
// 319.041 us; speedup vs baseline: 1.1790x; 1.0518x over previous
//
#include <hip/hip_runtime.h>
#include <hip/hip_bf16.h>

typedef unsigned short u16;
typedef float f32x4 __attribute__((ext_vector_type(4)));
typedef __bf16 bf16x8 __attribute__((ext_vector_type(8)));
typedef unsigned short su8v __attribute__((ext_vector_type(8)));
typedef unsigned short su4v __attribute__((ext_vector_type(4)));

#define BB 8
#define NHD 8
#define DD 128
#define NN 1024
#define DIM 1024
#define H3 3072
#define MM 8192
#define PTS 72   // P LDS row stride (u16)
// scale * log2(e), folded into Q weights so softmax is exp2(raw dot)
#define QSC (0.08838834764831845f * 1.4426950408889634f)

__constant__ int   d_IDX[16] = {0,1,2,3, 1,0,3,2, 2,3,0,1, 3,2,1,0};
__constant__ float d_SGN[16] = {1.f,-1.f,-1.f,-1.f, 1.f,1.f,1.f,-1.f,
                                1.f,-1.f,1.f,1.f,  1.f,1.f,-1.f,1.f};

__device__ __forceinline__ f32x4 mfma16(su8v a, su8v b, f32x4 c) {
  return __builtin_amdgcn_mfma_f32_16x16x32_bf16(
      __builtin_bit_cast(bf16x8, a), __builtin_bit_cast(bf16x8, b), c, 0, 0, 0);
}
__device__ __forceinline__ u16 f2b(float f) {  // RNE
  unsigned int u = __builtin_bit_cast(unsigned int, f);
  u += 0x7fffu + ((u >> 16) & 1u);
  return (u16)(u >> 16);
}
__device__ __forceinline__ float b2f(u16 v) {
  unsigned int u = ((unsigned int)v) << 16;
  return __builtin_bit_cast(float, u);
}
typedef const __attribute__((address_space(1))) unsigned int* gas_t;
typedef __attribute__((address_space(3))) unsigned int* las_t;
__device__ __forceinline__ void gll16(const u16* g, u16* l) {
  __builtin_amdgcn_global_load_lds((gas_t)g, (las_t)l, 16, 0, 0);
}

// ---------------------------------------------------------------------------
// prep_weff: effective weights [out_row][in_col] bf16; Q-rows pre-scaled by QSC
// ---------------------------------------------------------------------------
__global__ __launch_bounds__(256) void prep_weff(
    const float* __restrict__ wqkv, const float* __restrict__ wproj,
    u16* __restrict__ weffQ, u16* __restrict__ weffP) {
  int tid = blockIdx.x * 256 + threadIdx.x;
  int stride = gridDim.x * 256;
  for (int i = tid; i < H3 * DIM; i += stride) {
    int row = i >> 10, col = i & 1023;
    int q = row / 768, o = row - q * 768;
    int p = col >> 8, c = col & 255;
    float v = d_SGN[q * 4 + p] * wqkv[(d_IDX[q * 4 + p] * 768 + o) * 256 + c];
    if (o < 256) v *= QSC;  // Q rows
    weffQ[i] = f2b(v);
  }
  for (int i = tid; i < DIM * DIM; i += stride) {
    int row = i >> 10, col = i & 1023;
    int q = row >> 8, o = row & 255;
    int p = col >> 8, c = col & 255;
    weffP[i] = f2b(d_SGN[q * 4 + p] * wproj[(d_IDX[q * 4 + p] * 256 + o) * 256 + c]);
  }
}

// ---------------------------------------------------------------------------
// prep_x: x (B,Cc,4,N) fp32 -> Ax bf16 [8192 (b,n)][1024 (p,c)]
// ---------------------------------------------------------------------------
__global__ __launch_bounds__(256) void prep_x(
    const float* __restrict__ x, u16* __restrict__ Ax) {
  int id = blockIdx.x * 256 + threadIdx.x;
  const float4* xv = (const float4*)x;
  float4 f = xv[id];
  int n4 = id & 255;
  int rem = id >> 8;
  int p = rem & 3, c = (rem >> 2) & 255, b = rem >> 10;
  int col = p * 256 + c;
  size_t rbase = (size_t)(b * 1024 + n4 * 4) * 1024 + col;
  Ax[rbase] = f2b(f.x);
  Ax[rbase + 1024] = f2b(f.y);
  Ax[rbase + 2048] = f2b(f.z);
  Ax[rbase + 3072] = f2b(f.w);
}

// ---------------------------------------------------------------------------
// GEMM core: 128x128 tile, BK=64 (32 MFMA per barrier pair), gll staging.
// LDS rows 64 u16 = 8 x 16B blocks, XOR-swizzled (blk ^= row&7) so fragment
// ds_read_b128 across l16 covers all 32 banks (2-way alias = free).
// A/B-symmetric: callers choose orientation by argument order.
// ---------------------------------------------------------------------------
__device__ __forceinline__ void gemm_core2(
    const u16* __restrict__ Ag, const u16* __restrict__ Bg,
    u16* As, u16* Bs, int tid, f32x4 acc[4][4]) {
  int w = tid >> 6, lane = tid & 63, l16 = lane & 15, quad = lane >> 4;
  int mt = (w & 1) * 64, nt = (w >> 1) * 64;
  int srow = lane >> 3;                       // row&7 within staging
  int scol = ((lane & 7) ^ srow) * 8;         // swizzled global block
  int x7 = l16 & 7;                           // row&7 for fragment reads
  for (int k0 = 0; k0 < 1024; k0 += 64) {
    __syncthreads();
#pragma unroll
    for (int t = 0; t < 4; ++t) {
      int ci = w * 4 + t;
      int row = ci * 8 + srow;
      gll16(Ag + (size_t)row * 1024 + k0 + scol, As + ci * 512);
      gll16(Bg + (size_t)row * 1024 + k0 + scol, Bs + ci * 512);
    }
    __syncthreads();
#pragma unroll
    for (int kk = 0; kk < 2; ++kk) {
      su8v af[4], bf[4];
#pragma unroll
      for (int i = 0; i < 4; ++i)
        af[i] = *(const su8v*)(As + (mt + i * 16 + l16) * 64 +
                               ((kk * 4 + quad) ^ x7) * 8);
#pragma unroll
      for (int j = 0; j < 4; ++j)
        bf[j] = *(const su8v*)(Bs + (nt + j * 16 + l16) * 64 +
                               ((kk * 4 + quad) ^ x7) * 8);
#pragma unroll
      for (int i = 0; i < 4; ++i)
#pragma unroll
        for (int j = 0; j < 4; ++j)
          acc[i][j] = mfma16(af[i], bf[j], acc[i][j]);
    }
  }
}

// ---------------------------------------------------------------------------
// QKV GEMM. Each column-block (blockIdx.y, 128 chans) lies in exactly one of
// Q/K/V and one head. Orientation chosen per block so the C-layout's 4
// row-consecutive values per lane map onto the *contiguous* axis of the
// destination: Q/K (m=chan -> r=d-consecutive, store [bh][npos][d]);
// V (m=bn -> r=npos-consecutive, store V^T [bh][d][npos]). All stores b64.
// ---------------------------------------------------------------------------
__global__ __launch_bounds__(256) void gemm_qkv_mfma(
    const u16* __restrict__ Ax, const u16* __restrict__ weffQ,
    const float* __restrict__ bqkv,
    u16* __restrict__ Qb, u16* __restrict__ Kb, u16* __restrict__ VbT) {
  __shared__ u16 As[128 * 64];
  __shared__ u16 Bs[128 * 64];
  int m0 = blockIdx.x * 128;    // bn block
  int col0 = blockIdx.y * 128;  // chan block (row of weffQ)
  int qq = col0 / 768;          // quaternion component (uniform)
  int off = col0 - qq * 768;
  int sel = off >> 8;           // 0=Q 1=K 2=V (uniform)
  int head = (qq * 256 + (off & 255)) >> 7;  // uniform, block = one head
  int tid = threadIdx.x;
  int w = tid >> 6, lane = tid & 63, l16 = lane & 15, quad = lane >> 4;
  int mt = (w & 1) * 64, nt = (w >> 1) * 64;
  f32x4 acc[4][4];
#pragma unroll
  for (int i = 0; i < 4; ++i)
#pragma unroll
    for (int j = 0; j < 4; ++j) acc[i][j] = (f32x4){0.f, 0.f, 0.f, 0.f};

  if (sel == 2) {
    // ---- V: m=bn, n=chan ----
    gemm_core2(Ax + (size_t)m0 * 1024, weffQ + (size_t)col0 * 1024, As, Bs,
               tid, acc);
#pragma unroll
    for (int j = 0; j < 4; ++j) {
      int d = nt + j * 16 + l16;
      float bias = bqkv[col0 + nt + j * 16 + l16];
#pragma unroll
      for (int i = 0; i < 4; ++i) {
        int m = m0 + mt + i * 16 + quad * 4;
        int b = m >> 10, npos = m & 1023;
        int bh = b * NHD + head;
        su4v pk;
#pragma unroll
        for (int r = 0; r < 4; ++r) pk[r] = f2b(acc[i][j][r] + bias);
        *(su4v*)(VbT + ((size_t)bh * DD + d) * NN + npos) = pk;
      }
    }
  } else {
    // ---- Q/K: m=chan, n=bn ----
    gemm_core2(weffQ + (size_t)col0 * 1024, Ax + (size_t)m0 * 1024, As, Bs,
               tid, acc);
    u16* dst = (sel == 0) ? Qb : Kb;
    float sc = (sel == 0) ? (float)QSC : 1.0f;
#pragma unroll
    for (int i = 0; i < 4; ++i) {
      int dbase = mt + i * 16 + quad * 4;  // d of r=0 (mult of 4)
      float4 b4 = *(const float4*)(bqkv + col0 + dbase);
#pragma unroll
      for (int j = 0; j < 4; ++j) {
        int nglob = m0 + nt + j * 16 + l16;
        int b = nglob >> 10, npos = nglob & 1023;
        int bh = b * NHD + head;
        su4v pk;
        pk[0] = f2b(acc[i][j][0] + b4.x * sc);
        pk[1] = f2b(acc[i][j][1] + b4.y * sc);
        pk[2] = f2b(acc[i][j][2] + b4.z * sc);
        pk[3] = f2b(acc[i][j][3] + b4.w * sc);
        *(su4v*)(dst + ((size_t)bh * NN + npos) * DD + dbase) = pk;
      }
    }
  }
}

// ---------------------------------------------------------------------------
// Flash attention, split-K x2: 1024 blocks = half(2) x qt(8) x bh(64, low
// bits so all blocks of a bh share an XCD for K/V L2 reuse). Each block:
// 128 queries x 512 keys. Max-free exp2 softmax => partials merge additively:
// store unnormalized O (bf16) + row-sum l (fp32); merge kernel divides.
// ---------------------------------------------------------------------------
__global__ __launch_bounds__(256) void attn_mfma(
    const u16* __restrict__ Qb, const u16* __restrict__ Kb,
    const u16* __restrict__ VbT, u16* __restrict__ OP,
    float* __restrict__ LS) {
  __shared__ u16 Ks[64 * 128];     // 16384 B, xor-swizzled 16B blocks
  __shared__ u16 Vt[128 * 64];     // 16384 B, xor-swizzled 16B blocks
  __shared__ u16 Ps[4 * 32 * PTS]; // 18432 B
  int blk = blockIdx.x;
  int bh = blk & 63;               // low bits -> blk%8 == bh%8 (same XCD)
  int rest = blk >> 6;
  int qt = rest & 7;
  int half = rest >> 3;
  int n0 = qt * 128;
  int tid = threadIdx.x;
  int w = tid >> 6, lane = tid & 63, l16 = lane & 15, quad = lane >> 4;
  const u16* Qg = Qb + ((size_t)bh * NN + n0) * DD;
  const u16* Kg = Kb + (size_t)bh * NN * DD;
  const u16* Vg = VbT + (size_t)bh * DD * NN;
  u16* Pw = Ps + w * 32 * PTS;
  int x7 = l16 & 7;

  su8v qreg[2][4];  // B-fragment: n=q (l16), k=d
#pragma unroll
  for (int mi = 0; mi < 2; ++mi)
#pragma unroll
    for (int ch = 0; ch < 4; ++ch)
      qreg[mi][ch] = *(const su8v*)(Qg + (size_t)(w * 32 + mi * 16 + l16) * DD +
                                    ch * 32 + quad * 8);

  float ls[2] = {0.f, 0.f};  // per-lane partial row-sum for q = l16
  f32x4 accO[2][8];
#pragma unroll
  for (int mi = 0; mi < 2; ++mi)
#pragma unroll
    for (int dt = 0; dt < 8; ++dt) accO[mi][dt] = (f32x4){0.f, 0.f, 0.f, 0.f};

  for (int kt = 0; kt < 8; ++kt) {
    int c0 = half * 512 + kt * 64;
    __syncthreads();
#pragma unroll
    for (int t = 0; t < 4; ++t) {
      int ci = w * 4 + t;
      // K: rows of 256B = 16 x 16B blocks; block low-3-bits xor row&7
      int krow = ci * 4 + (lane >> 4);
      int kblk = (lane & 15) ^ (krow & 7);
      gll16(Kg + (size_t)(c0 + krow) * DD + kblk * 8, Ks + ci * 512);
      // V^T: rows of 128B = 8 x 16B blocks; xor-swizzled
      int dv = ci * 8 + (lane >> 3);
      int vblk = (lane & 7) ^ (dv & 7);
      gll16(Vg + (size_t)dv * NN + c0 + vblk * 8, Vt + ci * 512);
    }
    __syncthreads();

    // S^T[key][q]: A = K-frag (m=key), B = Q-frag (n=q)
    f32x4 sacc[2][4];
#pragma unroll
    for (int mi = 0; mi < 2; ++mi)
#pragma unroll
      for (int j = 0; j < 4; ++j) sacc[mi][j] = (f32x4){0.f, 0.f, 0.f, 0.f};
#pragma unroll
    for (int j = 0; j < 4; ++j) {
#pragma unroll
      for (int ch = 0; ch < 4; ++ch) {
        su8v kf = *(const su8v*)(Ks + (j * 16 + l16) * 128 +
                                 (((ch * 4 + quad) ^ x7) * 8));
        sacc[0][j] = mfma16(kf, qreg[0][ch], sacc[0][j]);
        sacc[1][j] = mfma16(kf, qreg[1][ch], sacc[1][j]);
      }
    }

    // p = 2^s; pack 4 key-contiguous values -> one b64 LDS write
#pragma unroll
    for (int mi = 0; mi < 2; ++mi)
#pragma unroll
      for (int j = 0; j < 4; ++j) {
        su4v pk;
#pragma unroll
        for (int r = 0; r < 4; ++r) {
          float p = __builtin_exp2f(sacc[mi][j][r]);
          ls[mi] += p;
          pk[r] = (u16)(__builtin_bit_cast(unsigned int, p) >> 16);
        }
        *(su4v*)(Pw + (mi * 16 + l16) * PTS + j * 16 + quad * 4) = pk;
      }

    // O += P V  (wave-local LDS round trip; DS pipe in-order per wave)
#pragma unroll
    for (int ch = 0; ch < 2; ++ch) {
      su8v pf0 = *(const su8v*)(Pw + l16 * PTS + ch * 32 + quad * 8);
      su8v pf1 = *(const su8v*)(Pw + (16 + l16) * PTS + ch * 32 + quad * 8);
#pragma unroll
      for (int dt = 0; dt < 8; ++dt) {
        su8v vf = *(const su8v*)(Vt + (dt * 16 + l16) * 64 +
                                 (((ch * 4 + quad) ^ x7) * 8));
        accO[0][dt] = mfma16(pf0, vf, accO[0][dt]);
        accO[1][dt] = mfma16(pf1, vf, accO[1][dt]);
      }
    }
  }

  // row-sum: reduce over quad lanes (bits 4,5) -> all lanes hold full sum
#pragma unroll
  for (int mi = 0; mi < 2; ++mi) {
    float s = ls[mi];
    s += __shfl_xor(s, 16, 64);
    s += __shfl_xor(s, 32, 64);
    ls[mi] = s;
  }
  size_t hb = (size_t)(half * 64 + bh);
  if (quad == 0) {
#pragma unroll
    for (int mi = 0; mi < 2; ++mi)
      LS[hb * NN + n0 + w * 32 + mi * 16 + l16] = ls[mi];
  }
  // store unnormalized O partial (bf16)
#pragma unroll
  for (int mi = 0; mi < 2; ++mi)
#pragma unroll
    for (int r = 0; r < 4; ++r) {
      int row = w * 32 + mi * 16 + quad * 4 + r;
      size_t base = (hb * NN + n0 + row) * DD;
#pragma unroll
      for (int dt = 0; dt < 8; ++dt)
        OP[base + dt * 16 + l16] = f2b(accO[mi][dt][r]);
    }
}

// ---------------------------------------------------------------------------
// merge: AO[b,n][head*128+d] = (O0 + O1) / (l0 + l1)
// ---------------------------------------------------------------------------
__global__ __launch_bounds__(256) void attn_merge(
    const u16* __restrict__ OP, const float* __restrict__ LS,
    u16* __restrict__ AO) {
  size_t idx = (size_t)blockIdx.x * 256 + threadIdx.x;  // 4-elem chunk id
  size_t e = idx * 4;
  int d = (int)(e & 127);
  size_t bhn = e >> 7;  // bh*1024 + n
  su4v a = *(const su4v*)(OP + bhn * DD + d);
  su4v b = *(const su4v*)(OP + (size_t)64 * NN * DD + bhn * DD + d);
  float inv = 1.0f / (LS[bhn] + LS[bhn + 64 * NN]);
  int bh = (int)(bhn >> 10), n = (int)(bhn & 1023);
  int bb = bh >> 3, head = bh & 7;
  su4v o;
#pragma unroll
  for (int r = 0; r < 4; ++r) o[r] = f2b((b2f(a[r]) + b2f(b[r])) * inv);
  *(su4v*)(AO + ((size_t)(bb * 1024 + n) * 1024) + head * 128 + d) = o;
}

// ---------------------------------------------------------------------------
// quaternion depthwise 3x3 conv (fp32) — writes PE term into workspace
// ---------------------------------------------------------------------------
__global__ __launch_bounds__(256) void qdwconv_kernel(
    const float* __restrict__ x, const float* __restrict__ wpe,
    const float* __restrict__ bpe, float* __restrict__ pe) {
  int blk = blockIdx.x;
  int co = blk & 255;
  int b = blk >> 8;
  __shared__ float pl[4][34 * 34];
  __shared__ float wsm[4][9];
  int tid = threadIdx.x;
  for (int i = tid; i < 4 * 34 * 34; i += 256) ((float*)pl)[i] = 0.f;
  if (tid < 36) wsm[tid / 9][tid % 9] = wpe[((tid / 9) * 256 + co) * 9 + tid % 9];
  __syncthreads();
  for (int i = tid; i < 4 * 1024; i += 256) {
    int p = i >> 10, n = i & 1023;
    int h = n >> 5, ww = n & 31;
    pl[p][(h + 1) * 34 + (ww + 1)] =
        x[(((size_t)b * 256 + co) * 4 + p) * 1024 + n];
  }
  __syncthreads();
  for (int n = tid; n < 1024; n += 256) {
    int h = n >> 5, ww = n & 31;
    float in[4][9];
#pragma unroll
    for (int p = 0; p < 4; ++p)
#pragma unroll
      for (int t = 0; t < 9; ++t)
        in[p][t] = pl[p][(h + t / 3) * 34 + (ww + t % 3)];
#pragma unroll
    for (int q = 0; q < 4; ++q) {
      float acc = bpe[q * 256 + co];
#pragma unroll
      for (int p = 0; p < 4; ++p) {
        int idx = d_IDX[q * 4 + p];
        float s = d_SGN[q * 4 + p];
        float sub = 0.f;
#pragma unroll
        for (int t = 0; t < 9; ++t) sub += in[p][t] * wsm[idx][t];
        acc += s * sub;
      }
      pe[(((size_t)b * 256 + co) * 4 + q) * 1024 + n] = acc;
    }
  }
}

// ---------------------------------------------------------------------------
// proj GEMM (swapped orientation): C[m=(q,o)][n=bn].
// Epilogue: out = PE + acc + bias (pure store — out has exactly one writer).
// ---------------------------------------------------------------------------
__global__ __launch_bounds__(256) void gemm_proj_mfma(
    const u16* __restrict__ AO, const u16* __restrict__ weffP,
    const float* __restrict__ bproj, const float* __restrict__ pe,
    float* __restrict__ out) {
  __shared__ u16 As[128 * 64];
  __shared__ u16 Bs[128 * 64];
  int n0 = blockIdx.x * 128;  // bn
  int m0 = blockIdx.y * 128;  // (q,o)
  int tid = threadIdx.x;
  f32x4 acc[4][4];
#pragma unroll
  for (int i = 0; i < 4; ++i)
#pragma unroll
    for (int j = 0; j < 4; ++j) acc[i][j] = (f32x4){0.f, 0.f, 0.f, 0.f};
  gemm_core2(weffP + (size_t)m0 * 1024, AO + (size_t)n0 * 1024, As, Bs, tid, acc);

  int w = tid >> 6, lane = tid & 63, l16 = lane & 15, quad = lane >> 4;
  int mt = (w & 1) * 64, nt = (w >> 1) * 64;
#pragma unroll
  for (int i = 0; i < 4; ++i) {
#pragma unroll
    for (int r = 0; r < 4; ++r) {
      int mrow = m0 + mt + i * 16 + quad * 4 + r;
      int q = mrow >> 8, o = mrow & 255;
      float bias = bproj[mrow];
#pragma unroll
      for (int j = 0; j < 4; ++j) {
        int n = n0 + nt + j * 16 + l16;
        int b = n >> 10, npos = n & 1023;
        size_t oidx = (((size_t)b * 256 + o) * 4 + q) * 1024 + npos;
        out[oidx] = pe[oidx] + acc[i][j][r] + bias;
      }
    }
  }
}

// ---------------------------------------------------------------------------
extern "C" void kernel_launch(void* const* d_in, const int* in_sizes, int n_in,
                              void* d_out, int out_size, void* d_ws,
                              size_t ws_size, hipStream_t stream) {
  const float* x      = (const float*)d_in[0];
  const float* w_qkv  = (const float*)d_in[1];
  const float* b_qkv  = (const float*)d_in[2];
  const float* w_proj = (const float*)d_in[3];
  const float* b_proj = (const float*)d_in[4];
  const float* w_pe   = (const float*)d_in[5];
  const float* b_pe   = (const float*)d_in[6];
  float* out = (float*)d_out;

  u16* ws = (u16*)d_ws;
  u16* weffQ = ws;                                   // 3072*1024
  u16* weffP = weffQ + (size_t)H3 * DIM;             // 1024*1024
  u16* Ax    = weffP + (size_t)DIM * DIM;            // 8192*1024
  u16* Qb    = Ax + (size_t)MM * DIM;                // 64*1024*128
  u16* Kb    = Qb + (size_t)BB * NHD * NN * DD;      // 64*1024*128
  u16* VbT   = Kb + (size_t)BB * NHD * NN * DD;      // 64*128*1024
  u16* AO    = VbT + (size_t)BB * NHD * DD * NN;     // 8192*1024
  float* PE  = (float*)(AO + (size_t)MM * DIM);      // 8192*1024 fp32
  u16* OP    = (u16*)(PE + (size_t)MM * DIM);        // 2*64*1024*128 bf16
  float* LS  = (float*)(OP + (size_t)2 * 64 * NN * DD);  // 2*64*1024 fp32
  // total ~160 MB scratch

  hipLaunchKernelGGL(prep_weff, dim3(4096), dim3(256), 0, stream,
                     w_qkv, w_proj, weffQ, weffP);
  hipLaunchKernelGGL(prep_x, dim3(8192), dim3(256), 0, stream, x, Ax);
  hipLaunchKernelGGL(gemm_qkv_mfma, dim3(MM / 128, H3 / 128), dim3(256), 0,
                     stream, Ax, weffQ, b_qkv, Qb, Kb, VbT);
  hipLaunchKernelGGL(attn_mfma, dim3(1024), dim3(256), 0, stream,
                     Qb, Kb, VbT, OP, LS);
  hipLaunchKernelGGL(attn_merge, dim3((64 * NN * DD) / (256 * 4)), dim3(256),
                     0, stream, OP, LS, AO);
  hipLaunchKernelGGL(qdwconv_kernel, dim3(BB * 256), dim3(256), 0, stream,
                     x, w_pe, b_pe, PE);
  hipLaunchKernelGGL(gemm_proj_mfma, dim3(MM / 128, DIM / 128), dim3(256), 0,
                     stream, AO, weffP, b_proj, PE, out);
}